// Round 1
// baseline (238.697 us; speedup 1.0000x reference)
//
#include <hip/hip_runtime.h>
#include <hip/hip_bf16.h>
#include <cmath>

#define Bb 8
#define Tt 4096
#define Dd 512
#define Hh 512
#define Mm (Bb*Tt)

// GEMM tiling
#define BM 128
#define BN 64
#define BK 64
#define LDA 72   // padded row stride in bf16 elems (64 + 8) -> 144B rows, breaks 16-way bank conflict

// scan chunking
#define NCHUNK 64
#define CLEN (Tt/NCHUNK)   // 64

typedef unsigned short u16;
typedef __attribute__((ext_vector_type(8))) short bf16x8;
typedef __attribute__((ext_vector_type(4))) float f32x4;

__device__ __forceinline__ u16 f2bf(float f) {
    unsigned u = __float_as_uint(f);
    u += 0x7fffu + ((u >> 16) & 1u);   // RNE
    return (u16)(u >> 16);
}

__device__ __forceinline__ float softplusf(float x) {
    // log(1+exp(x)), stable
    return fmaxf(x, 0.0f) + log1pf(expf(-fabsf(x)));
}

// ---------------- kernel 0: fp32 -> bf16 convert (vector 8/thread) ----------------
__global__ void cvt_kernel(const float* __restrict__ in, u16* __restrict__ out, int n8) {
    int i = blockIdx.x * blockDim.x + threadIdx.x;
    if (i >= n8) return;
    float4 a = reinterpret_cast<const float4*>(in)[i*2];
    float4 b = reinterpret_cast<const float4*>(in)[i*2+1];
    union { u16 u[8]; uint4 v; } r;
    r.u[0]=f2bf(a.x); r.u[1]=f2bf(a.y); r.u[2]=f2bf(a.z); r.u[3]=f2bf(a.w);
    r.u[4]=f2bf(b.x); r.u[5]=f2bf(b.y); r.u[6]=f2bf(b.z); r.u[7]=f2bf(b.w);
    reinterpret_cast<uint4*>(out)[i] = r.v;
}

// ---------------- kernel 1: fused 3-gate GEMM + gate math ----------------
// z_g[m][h] = sum_d x[m][d] * W_g[h][d]  (B^T-style GEMM), then
// f = sigmoid(-(sp(-zf)-sp(-zi))), v = sigmoid(diff)*g(zh)
// F -> d_out (scratch reuse), V -> ws
__global__ __launch_bounds__(256, 2)
void gate_gemm(const u16* __restrict__ xb,      // [Mm][Dd] bf16
               const u16* __restrict__ wb,      // [3][Hh][Dd] bf16
               const float* __restrict__ b_f, const float* __restrict__ b_i,
               const float* __restrict__ b_h,
               float* Fo, float* Vo)
{
    __shared__ u16 As[BM][LDA];
    __shared__ u16 Ws[3][BN][LDA];

    const int m0 = blockIdx.x * BM;
    const int n0 = blockIdx.y * BN;
    const int tid = threadIdx.x;
    const int lane = tid & 63;
    const int wid = tid >> 6;
    const int wm = wid >> 1;    // 0..1 (M direction, 64 rows each)
    const int wn = wid & 1;     // 0..1 (N direction, 32 cols each)

    f32x4 acc[3][4][2];
    #pragma unroll
    for (int g = 0; g < 3; ++g)
        #pragma unroll
        for (int mi = 0; mi < 4; ++mi)
            #pragma unroll
            for (int ni = 0; ni < 2; ++ni)
                acc[g][mi][ni] = (f32x4){0.f,0.f,0.f,0.f};

    for (int k0 = 0; k0 < Dd; k0 += BK) {
        __syncthreads();   // protect previous iteration's reads
        // stage A: 128 rows x 64 k (bf16) = 1024 16B segs, 4/thread
        #pragma unroll
        for (int s = 0; s < 4; ++s) {
            int seg = tid + s * 256;
            int row = seg >> 3;
            int c8  = (seg & 7) * 8;
            *reinterpret_cast<uint4*>(&As[row][c8]) =
                *reinterpret_cast<const uint4*>(xb + (size_t)(m0 + row) * Dd + k0 + c8);
        }
        // stage W (3 gates): 3 x 64 x 64 = 1536 segs, 6/thread
        #pragma unroll
        for (int s = 0; s < 6; ++s) {
            int seg = tid + s * 256;
            int g   = seg >> 9;
            int s2  = seg & 511;
            int row = s2 >> 3;
            int c8  = (s2 & 7) * 8;
            *reinterpret_cast<uint4*>(&Ws[g][row][c8]) =
                *reinterpret_cast<const uint4*>(wb + ((size_t)g * Hh + n0 + row) * Dd + k0 + c8);
        }
        __syncthreads();

        #pragma unroll
        for (int s = 0; s < 2; ++s) {   // two K=32 sub-steps
            const int kb = s * 32 + (lane >> 4) * 8;
            bf16x8 a[4];
            #pragma unroll
            for (int mi = 0; mi < 4; ++mi)
                a[mi] = *reinterpret_cast<const bf16x8*>(&As[wm*64 + mi*16 + (lane & 15)][kb]);
            bf16x8 w[3][2];
            #pragma unroll
            for (int g = 0; g < 3; ++g)
                #pragma unroll
                for (int ni = 0; ni < 2; ++ni)
                    w[g][ni] = *reinterpret_cast<const bf16x8*>(&Ws[g][wn*32 + ni*16 + (lane & 15)][kb]);
            #pragma unroll
            for (int g = 0; g < 3; ++g)
                #pragma unroll
                for (int mi = 0; mi < 4; ++mi)
                    #pragma unroll
                    for (int ni = 0; ni < 2; ++ni)
                        acc[g][mi][ni] = __builtin_amdgcn_mfma_f32_16x16x32_bf16(
                            a[mi], w[g][ni], acc[g][mi][ni], 0, 0, 0);
        }
    }

    // epilogue: gate math, store f and v
    const int col = lane & 15;
    const int rbase = (lane >> 4) * 4;
    #pragma unroll
    for (int ni = 0; ni < 2; ++ni) {
        int h = n0 + wn*32 + ni*16 + col;
        float bfv = b_f[h], biv = b_i[h], bhv = b_h[h];
        #pragma unroll
        for (int mi = 0; mi < 4; ++mi) {
            #pragma unroll
            for (int r = 0; r < 4; ++r) {
                int m = m0 + wm*64 + mi*16 + rbase + r;
                float zf = acc[0][mi][ni][r] + bfv;
                float zi = acc[1][mi][ni][r] + biv;
                float zh = acc[2][mi][ni][r] + bhv;
                float diff = softplusf(-zf) - softplusf(-zi);
                float ig = 1.0f / (1.0f + expf(-diff));   // sigmoid(diff)
                float fg = 1.0f / (1.0f + expf(diff));    // sigmoid(-diff) = 1-ig
                float gv = (zh >= 0.0f) ? (zh + 0.5f) : (1.0f / (1.0f + expf(-zh)));
                size_t idx = (size_t)m * Hh + h;
                Fo[idx] = fg;
                Vo[idx] = ig * gv;
            }
        }
    }
}

// ---------------- scan pass 1: per-chunk composites ----------------
// h_end = Fp * h_start + Vp over CLEN steps
__global__ void scan_pass1(const float* __restrict__ Fo, const float* __restrict__ Vo,
                           float* __restrict__ Fc, float* __restrict__ Vc)
{
    int h = blockIdx.x * 256 + threadIdx.x;   // gridDim.x = Hh/256 = 2
    int b = blockIdx.y;
    int ch = blockIdx.z;
    size_t base = ((size_t)b * Tt + (size_t)ch * CLEN) * Hh + h;
    float Fp = 1.0f, Vp = 0.0f;
    #pragma unroll 4
    for (int t = 0; t < CLEN; ++t) {
        float f = Fo[base + (size_t)t * Hh];
        float v = Vo[base + (size_t)t * Hh];
        Vp = f * Vp + v;
        Fp *= f;
    }
    int ci = (b * NCHUNK + ch) * Hh + h;
    Fc[ci] = Fp;
    Vc[ci] = Vp;
}

// ---------------- scan pass 2: scan over chunk composites ----------------
__global__ void scan_pass2(const float* __restrict__ h0,
                           const float* __restrict__ Fc, const float* __restrict__ Vc,
                           float* __restrict__ Hs)
{
    int h = threadIdx.x;      // 512 threads
    int b = blockIdx.x;       // 8 blocks
    float x = h0[b * Hh + h];
    float hh = (x >= 0.0f) ? (x + 0.5f) : (1.0f / (1.0f + expf(-x)));  // g(h_0)
    #pragma unroll 8
    for (int ch = 0; ch < NCHUNK; ++ch) {
        int ci = (b * NCHUNK + ch) * Hh + h;
        Hs[ci] = hh;                    // h at chunk start
        hh = Fc[ci] * hh + Vc[ci];
    }
}

// ---------------- scan pass 3: apply chunks, write outputs ----------------
// NOTE: Fo aliases out; per element we read Fo[idx] strictly before writing out[idx]
__global__ void scan_pass3(const float* Fo, const float* __restrict__ Vo,
                           const float* __restrict__ Hs, float* out)
{
    int h = blockIdx.x * 256 + threadIdx.x;
    int b = blockIdx.y;
    int ch = blockIdx.z;
    float hh = Hs[(b * NCHUNK + ch) * Hh + h];
    size_t base = ((size_t)b * Tt + (size_t)ch * CLEN) * Hh + h;
    #pragma unroll 4
    for (int t = 0; t < CLEN; ++t) {
        size_t idx = base + (size_t)t * Hh;
        float f = Fo[idx];
        float v = Vo[idx];
        hh = f * hh + v;
        out[idx] = hh;
    }
}

extern "C" void kernel_launch(void* const* d_in, const int* in_sizes, int n_in,
                              void* d_out, int out_size, void* d_ws, size_t ws_size,
                              hipStream_t stream) {
    const float* x   = (const float*)d_in[0];
    const float* h0  = (const float*)d_in[1];
    const float* W_f = (const float*)d_in[2];
    const float* b_f = (const float*)d_in[3];
    const float* W_i = (const float*)d_in[4];
    const float* b_i = (const float*)d_in[5];
    const float* W_h = (const float*)d_in[6];
    const float* b_h = (const float*)d_in[7];
    float* out = (float*)d_out;

    // workspace layout
    char* ws = (char*)d_ws;
    u16*  xb = (u16*)ws;                                        // Mm*Dd bf16 = 32MB
    u16*  wbuf = (u16*)(ws + (size_t)Mm * Dd * 2);              // 3*Hh*Dd bf16 = 1.5MB
    float* Vo = (float*)(ws + (size_t)Mm * Dd * 2 + (size_t)3 * Hh * Dd * 2); // Mm*Hh f32 = 64MB
    float* Fc = Vo + (size_t)Mm * Hh;                           // Bb*NCHUNK*Hh
    float* Vc = Fc + (size_t)Bb * NCHUNK * Hh;
    float* Hs = Vc + (size_t)Bb * NCHUNK * Hh;
    float* Fo = out;   // reuse output buffer as F scratch

    // 0) converts
    {
        int n8 = Mm * Dd / 8;                                   // 2,097,152
        cvt_kernel<<<n8 / 256, 256, 0, stream>>>(x, xb, n8);
        int w8 = Hh * Dd / 8;                                   // 32,768
        cvt_kernel<<<w8 / 256, 256, 0, stream>>>(W_f, wbuf + 0 * (size_t)Hh * Dd, w8);
        cvt_kernel<<<w8 / 256, 256, 0, stream>>>(W_i, wbuf + 1 * (size_t)Hh * Dd, w8);
        cvt_kernel<<<w8 / 256, 256, 0, stream>>>(W_h, wbuf + 2 * (size_t)Hh * Dd, w8);
    }

    // 1) fused 3-gate GEMM + gate math
    {
        dim3 grid(Mm / BM, Hh / BN);   // 256 x 8
        gate_gemm<<<grid, 256, 0, stream>>>(xb, wbuf, b_f, b_i, b_h, Fo, Vo);
    }

    // 2) chunked scan
    {
        dim3 g1(Hh / 256, Bb, NCHUNK);   // 2 x 8 x 64
        scan_pass1<<<g1, 256, 0, stream>>>(Fo, Vo, Fc, Vc);
        scan_pass2<<<Bb, Hh, 0, stream>>>(h0, Fc, Vc, Hs);
        scan_pass3<<<g1, 256, 0, stream>>>(Fo, Vo, Hs, out);
    }
}

// Round 2
// 122.202 us; speedup vs baseline: 1.9533x; 1.9533x over previous
//
#include <hip/hip_runtime.h>
#include <hip/hip_bf16.h>
#include <cmath>

#define Bb 8
#define Tt 4096
#define Dd 512
#define Hh 512
#define Mm (Bb*Tt)

// GEMM tiling
#define BM 128
#define BN 64
#define BK 64

// scan chunking
#define NCHUNK 64
#define CLEN (Tt/NCHUNK)   // 64

typedef unsigned short u16;
typedef unsigned int   u32;
typedef __attribute__((ext_vector_type(8))) short bf16x8;
typedef __attribute__((ext_vector_type(4))) float f32x4;
typedef __attribute__((address_space(3))) char lds_char;

__device__ __forceinline__ u16 f2bf(float f) {
    u32 u = __float_as_uint(f);
    u += 0x7fffu + ((u >> 16) & 1u);   // RNE
    return (u16)(u >> 16);
}
__device__ __forceinline__ float bf2f_lo(u32 p) { return __uint_as_float(p << 16); }
__device__ __forceinline__ float bf2f_hi(u32 p) { return __uint_as_float(p & 0xffff0000u); }

__device__ __forceinline__ void gl2lds16(const void* g, lds_char* l) {
    __builtin_amdgcn_global_load_lds(
        (const __attribute__((address_space(1))) u32*)g,
        (__attribute__((address_space(3))) u32*)l, 16, 0, 0);
}

// ---------------- kernel 0: fp32 -> bf16 convert ----------------
__global__ void cvt_kernel(const float* __restrict__ in, u16* __restrict__ out, int n8) {
    int i = blockIdx.x * blockDim.x + threadIdx.x;
    if (i >= n8) return;
    float4 a = reinterpret_cast<const float4*>(in)[i*2];
    float4 b = reinterpret_cast<const float4*>(in)[i*2+1];
    union { u16 u[8]; uint4 v; } r;
    r.u[0]=f2bf(a.x); r.u[1]=f2bf(a.y); r.u[2]=f2bf(a.z); r.u[3]=f2bf(a.w);
    r.u[4]=f2bf(b.x); r.u[5]=f2bf(b.y); r.u[6]=f2bf(b.z); r.u[7]=f2bf(b.w);
    reinterpret_cast<uint4*>(out)[i] = r.v;
}

// ---------------- kernel 1: fused 3-gate GEMM + gate math ----------------
// LDS layout: A tile [128][64] bf16 (16 KB) then W tile [3*64][64] (24 KB),
// both linear rows of 128 B with XOR swizzle byte ^= ((row&7)<<4) applied
// on the GLOBAL source (staging) and on the ds_read address (reading).
__global__ __launch_bounds__(256, 2)
void gate_gemm(const u16* __restrict__ xb,      // [Mm][Dd] bf16
               const u16* __restrict__ wb,      // [3][Hh][Dd] bf16
               const float* __restrict__ b_f, const float* __restrict__ b_i,
               const float* __restrict__ b_h,
               u32* __restrict__ FV)            // packed bf16 f | v<<16
{
    __shared__ __align__(128) u16 sbuf[(BM + 3*BN) * BK];   // 40 KB

    const int tid  = threadIdx.x;
    const int lane = tid & 63;
    const int w    = tid >> 6;
    const int wm   = w >> 1;    // 0..1
    const int wn   = w & 1;     // 0..1

    // XCD-bijective swizzle: each XCD gets a contiguous chunk of m-panels,
    // n iterates fastest inside -> A panel (128 KB) stays hot in that XCD's L2.
    const int bid = blockIdx.x;
    const int lg  = (bid >> 3) + (bid & 7) * ((int)gridDim.x >> 3);
    const int m0  = (lg >> 3) * BM;
    const int n0  = (lg & 7) * BN;

    // ---- staging addresses (pre-swizzled global source, linear LDS dest) ----
    const int lrow = lane >> 3;                       // row within 8-row group
    const int scb  = ((lane & 7) * 16) ^ (lrow << 4); // swizzled col-byte
    lds_char* Lb = (lds_char*)&sbuf[0];

    const char* ap[4]; lds_char* aL[4];
    #pragma unroll
    for (int s = 0; s < 4; ++s) {
        ap[s] = (const char*)xb + ((size_t)(m0 + w*32 + s*8 + lrow) << 10) + scb;
        aL[s] = Lb + (w*4 + s) * 1024;
    }
    const char* wp[6]; lds_char* wL[6];
    #pragma unroll
    for (int s = 0; s < 6; ++s) {
        int jj = w*6 + s;                 // 0..23 over [3][64] rows /8
        int g  = jj >> 3;
        int hg = (jj & 7) * 8 + lrow;
        wp[s] = (const char*)wb + ((size_t)(g*Hh + n0 + hg) << 10) + scb;
        wL[s] = Lb + 16384 + jj * 1024;
    }

    // ---- fragment read offsets (swizzled) ----
    const char* sA  = (const char*)&sbuf[0];
    const int arow  = wm*64 + (lane & 15);
    const int wrow  = wn*32 + (lane & 15);
    const int sw    = (lane & 7) << 4;
    int acol[2];
    #pragma unroll
    for (int s = 0; s < 2; ++s)
        acol[s] = ((s*64) | ((lane >> 4) * 16)) ^ sw;

    f32x4 acc[3][4][2];
    #pragma unroll
    for (int g = 0; g < 3; ++g)
        #pragma unroll
        for (int mi = 0; mi < 4; ++mi)
            #pragma unroll
            for (int ni = 0; ni < 2; ++ni)
                acc[g][mi][ni] = (f32x4){0.f,0.f,0.f,0.f};

    for (int k0 = 0; k0 < Dd; k0 += BK) {
        __syncthreads();   // previous tile fully consumed
        #pragma unroll
        for (int s = 0; s < 4; ++s) { gl2lds16(ap[s], aL[s]); ap[s] += 2*BK; }
        #pragma unroll
        for (int s = 0; s < 6; ++s) { gl2lds16(wp[s], wL[s]); wp[s] += 2*BK; }
        __syncthreads();   // drains vmcnt(0): tile visible

        #pragma unroll
        for (int s = 0; s < 2; ++s) {
            bf16x8 a[4];
            #pragma unroll
            for (int mi = 0; mi < 4; ++mi)
                a[mi] = *(const bf16x8*)(sA + ((arow + mi*16) << 7) + acol[s]);
            #pragma unroll
            for (int g = 0; g < 3; ++g) {
                bf16x8 w0 = *(const bf16x8*)(sA + 16384 + g*8192 + (wrow << 7) + acol[s]);
                bf16x8 w1 = *(const bf16x8*)(sA + 16384 + g*8192 + ((wrow + 16) << 7) + acol[s]);
                #pragma unroll
                for (int mi = 0; mi < 4; ++mi) {
                    acc[g][mi][0] = __builtin_amdgcn_mfma_f32_16x16x32_bf16(a[mi], w0, acc[g][mi][0], 0,0,0);
                    acc[g][mi][1] = __builtin_amdgcn_mfma_f32_16x16x32_bf16(a[mi], w1, acc[g][mi][1], 0,0,0);
                }
            }
        }
    }

    // ---- epilogue: fg = I/(F+I), ig = F/(F+I), F=1+e^-zf, I=1+e^-zi ----
    const int col = lane & 15;
    const int rb  = (lane >> 4) * 4;
    #pragma unroll
    for (int ni = 0; ni < 2; ++ni) {
        const int h = n0 + wn*32 + ni*16 + col;
        const float bfv = b_f[h], biv = b_i[h], bhv = b_h[h];
        #pragma unroll
        for (int mi = 0; mi < 4; ++mi) {
            #pragma unroll
            for (int r = 0; r < 4; ++r) {
                const int m = m0 + wm*64 + mi*16 + rb + r;
                float zf = acc[0][mi][ni][r] + bfv;
                float zi = acc[1][mi][ni][r] + biv;
                float zh = acc[2][mi][ni][r] + bhv;
                float ef = __expf(fminf(-zf, 60.0f));
                float ei = __expf(fminf(-zi, 60.0f));
                float rr = __builtin_amdgcn_rcpf(2.0f + ef + ei);
                float fg = (1.0f + ei) * rr;
                float ig = (1.0f + ef) * rr;
                float eh = __expf(fminf(-zh, 60.0f));
                float gv = (zh >= 0.0f) ? (zh + 0.5f) : __builtin_amdgcn_rcpf(1.0f + eh);
                float vv = ig * gv;
                FV[(size_t)m * Hh + h] = (u32)f2bf(fg) | ((u32)f2bf(vv) << 16);
            }
        }
    }
}

// ---------------- scan pass 1: per-chunk composites ----------------
__global__ void scan_pass1(const u32* __restrict__ FV,
                           float2* __restrict__ Fc2, float2* __restrict__ Vc2)
{
    const int t2 = threadIdx.x;               // h-pair 0..255
    const int b = blockIdx.x, ch = blockIdx.y;
    const uint2* p = (const uint2*)FV;
    size_t base = ((size_t)b * Tt + (size_t)ch * CLEN) * (Hh/2) + t2;
    float F0=1.f, V0=0.f, F1=1.f, V1=0.f;
    #pragma unroll 8
    for (int t = 0; t < CLEN; ++t) {
        uint2 fv = p[base + (size_t)t * (Hh/2)];
        V0 = fmaf(bf2f_lo(fv.x), V0, bf2f_hi(fv.x)); F0 *= bf2f_lo(fv.x);
        V1 = fmaf(bf2f_lo(fv.y), V1, bf2f_hi(fv.y)); F1 *= bf2f_lo(fv.y);
    }
    int ci = (b * NCHUNK + ch) * (Hh/2) + t2;
    Fc2[ci] = make_float2(F0, F1);
    Vc2[ci] = make_float2(V0, V1);
}

// ---------------- scan pass 2: scan over chunk composites ----------------
__global__ void scan_pass2(const float* __restrict__ h0,
                           const float* __restrict__ Fc, const float* __restrict__ Vc,
                           float* __restrict__ Hs)
{
    int h = threadIdx.x;      // 512
    int b = blockIdx.x;       // 8
    float x = h0[b * Hh + h];
    float hh = (x >= 0.f) ? (x + 0.5f) : __builtin_amdgcn_rcpf(1.f + __expf(-x));
    #pragma unroll 8
    for (int ch = 0; ch < NCHUNK; ++ch) {
        int ci = (b * NCHUNK + ch) * Hh + h;
        Hs[ci] = hh;
        hh = fmaf(Fc[ci], hh, Vc[ci]);
    }
}

// ---------------- scan pass 3: apply chunks, write outputs ----------------
__global__ void scan_pass3(const u32* __restrict__ FV,
                           const float2* __restrict__ Hs2, float2* __restrict__ out2)
{
    const int t2 = threadIdx.x;
    const int b = blockIdx.x, ch = blockIdx.y;
    const uint2* p = (const uint2*)FV;
    float2 hh = Hs2[(b * NCHUNK + ch) * (Hh/2) + t2];
    size_t base = ((size_t)b * Tt + (size_t)ch * CLEN) * (Hh/2) + t2;
    #pragma unroll 4
    for (int t = 0; t < CLEN; ++t) {
        size_t idx = base + (size_t)t * (Hh/2);
        uint2 fv = p[idx];
        hh.x = fmaf(bf2f_lo(fv.x), hh.x, bf2f_hi(fv.x));
        hh.y = fmaf(bf2f_lo(fv.y), hh.y, bf2f_hi(fv.y));
        out2[idx] = hh;
    }
}

extern "C" void kernel_launch(void* const* d_in, const int* in_sizes, int n_in,
                              void* d_out, int out_size, void* d_ws, size_t ws_size,
                              hipStream_t stream) {
    const float* x   = (const float*)d_in[0];
    const float* h0  = (const float*)d_in[1];
    const float* W_f = (const float*)d_in[2];
    const float* b_f = (const float*)d_in[3];
    const float* W_i = (const float*)d_in[4];
    const float* b_i = (const float*)d_in[5];
    const float* W_h = (const float*)d_in[6];
    const float* b_h = (const float*)d_in[7];
    float* out = (float*)d_out;

    // workspace layout
    char* ws = (char*)d_ws;
    u16*  xb   = (u16*)ws;                                       // 32 MB
    u16*  wbuf = (u16*)(ws + (size_t)Mm * Dd * 2);               // 1.5 MB
    u32*  FV   = (u32*)(ws + (size_t)Mm * Dd * 2 + (size_t)3 * Hh * Dd * 2); // 64 MB
    float* Fc  = (float*)(FV + (size_t)Mm * Hh);                 // 1 MB
    float* Vc  = Fc + (size_t)Bb * NCHUNK * Hh;                  // 1 MB
    float* Hs  = Vc + (size_t)Bb * NCHUNK * Hh;                  // 1 MB

    // 0) converts
    {
        int n8 = Mm * Dd / 8;
        cvt_kernel<<<n8 / 256, 256, 0, stream>>>(x, xb, n8);
        int w8 = Hh * Dd / 8;
        cvt_kernel<<<w8 / 256, 256, 0, stream>>>(W_f, wbuf + 0 * (size_t)Hh * Dd, w8);
        cvt_kernel<<<w8 / 256, 256, 0, stream>>>(W_i, wbuf + 1 * (size_t)Hh * Dd, w8);
        cvt_kernel<<<w8 / 256, 256, 0, stream>>>(W_h, wbuf + 2 * (size_t)Hh * Dd, w8);
    }

    // 1) fused 3-gate GEMM + gate math
    gate_gemm<<<(Mm / BM) * (Hh / BN), 256, 0, stream>>>(xb, wbuf, b_f, b_i, b_h, FV);

    // 2) chunked scan
    {
        dim3 g1(Bb, NCHUNK);
        scan_pass1<<<g1, 256, 0, stream>>>(FV, (float2*)Fc, (float2*)Vc);
        scan_pass2<<<Bb, Hh, 0, stream>>>(h0, Fc, Vc, Hs);
        scan_pass3<<<g1, 256, 0, stream>>>(FV, (const float2*)Hs, (float2*)out);
    }
}

// Round 3
// 115.783 us; speedup vs baseline: 2.0616x; 1.0554x over previous
//
#include <hip/hip_runtime.h>
#include <hip/hip_bf16.h>
#include <cmath>

#define Bb 8
#define Tt 4096
#define Dd 512
#define Hh 512
#define Mm (Bb*Tt)

// GEMM tiling
#define BM 128
#define BN 64
#define BK 64
#define LDSHALF 20480           // u16 elems per buffer: (BM + 3*BN)*BK
#define LDSHALFB 40960          // bytes per buffer

// scan chunking
#define NCHUNK 64
#define CLEN (Tt/NCHUNK)   // 64

typedef unsigned short u16;
typedef unsigned int   u32;
typedef __attribute__((ext_vector_type(8))) short bf16x8;
typedef __attribute__((ext_vector_type(4))) float f32x4;
typedef __attribute__((address_space(3))) char lds_char;

__device__ __forceinline__ u16 f2bf(float f) {
    u32 u = __float_as_uint(f);
    u += 0x7fffu + ((u >> 16) & 1u);   // RNE
    return (u16)(u >> 16);
}
__device__ __forceinline__ float bf2f_lo(u32 p) { return __uint_as_float(p << 16); }
__device__ __forceinline__ float bf2f_hi(u32 p) { return __uint_as_float(p & 0xffff0000u); }

__device__ __forceinline__ void gl2lds16(const void* g, lds_char* l) {
    __builtin_amdgcn_global_load_lds(
        (const __attribute__((address_space(1))) u32*)g,
        (__attribute__((address_space(3))) u32*)l, 16, 0, 0);
}

// ---------------- kernel 0a: fp32 -> bf16 convert (x) ----------------
__global__ void cvt_kernel(const float* __restrict__ in, u16* __restrict__ out, int n8) {
    int i = blockIdx.x * blockDim.x + threadIdx.x;
    if (i >= n8) return;
    float4 a = reinterpret_cast<const float4*>(in)[i*2];
    float4 b = reinterpret_cast<const float4*>(in)[i*2+1];
    union { u16 u[8]; uint4 v; } r;
    r.u[0]=f2bf(a.x); r.u[1]=f2bf(a.y); r.u[2]=f2bf(a.z); r.u[3]=f2bf(a.w);
    r.u[4]=f2bf(b.x); r.u[5]=f2bf(b.y); r.u[6]=f2bf(b.z); r.u[7]=f2bf(b.w);
    reinterpret_cast<uint4*>(out)[i] = r.v;
}

// ---------------- kernel 0b: convert the 3 weight matrices in one launch ----------------
__global__ void cvt_w_kernel(const float* __restrict__ wf, const float* __restrict__ wi,
                             const float* __restrict__ wh, u16* __restrict__ out, int n8) {
    int i = blockIdx.x * blockDim.x + threadIdx.x;
    if (i >= n8) return;
    const float* in = (blockIdx.y == 0) ? wf : (blockIdx.y == 1) ? wi : wh;
    u16* o = out + (size_t)blockIdx.y * Hh * Dd;
    float4 a = reinterpret_cast<const float4*>(in)[i*2];
    float4 b = reinterpret_cast<const float4*>(in)[i*2+1];
    union { u16 u[8]; uint4 v; } r;
    r.u[0]=f2bf(a.x); r.u[1]=f2bf(a.y); r.u[2]=f2bf(a.z); r.u[3]=f2bf(a.w);
    r.u[4]=f2bf(b.x); r.u[5]=f2bf(b.y); r.u[6]=f2bf(b.z); r.u[7]=f2bf(b.w);
    reinterpret_cast<uint4*>(o)[i] = r.v;
}

// ---------------- kernel 1: fused 3-gate GEMM + gate math, 2-phase dbuf ----------------
// LDS per buffer: A tile [128][64] bf16 (16 KB) then W tile [3*64][64] (24 KB),
// linear 128 B rows, XOR swizzle byte ^= ((row&7)<<4) applied on the GLOBAL
// source (staging) and on the ds_read address (reading). Two buffers (80 KB):
// steady state issues next tile's global_load_lds BEFORE computing current
// tile; the single __syncthreads() per K-tile drains vmcnt+lgkm (T3 min-2ph).
__global__ __launch_bounds__(256, 2)
void gate_gemm(const u16* __restrict__ xb,      // [Mm][Dd] bf16
               const u16* __restrict__ wb,      // [3][Hh][Dd] bf16
               const float* __restrict__ b_f, const float* __restrict__ b_i,
               const float* __restrict__ b_h,
               u32* __restrict__ FV)            // packed bf16 f | v<<16
{
    __shared__ __align__(128) u16 sbuf[2 * LDSHALF];   // 80 KB

    const int tid  = threadIdx.x;
    const int lane = tid & 63;
    const int w    = tid >> 6;
    const int wm   = w >> 1;    // 0..1
    const int wn   = w & 1;     // 0..1

    // XCD-bijective swizzle: consecutive-n blocks stay on one XCD -> A panel L2-hot
    const int bid = blockIdx.x;
    const int lg  = (bid >> 3) + (bid & 7) * ((int)gridDim.x >> 3);
    const int m0  = (lg >> 3) * BM;
    const int n0  = (lg & 7) * BN;

    // ---- staging addresses (pre-swizzled global source, linear LDS dest) ----
    const int lrow = lane >> 3;                       // row within 8-row group
    const int scb  = ((lane & 7) * 16) ^ (lrow << 4); // swizzled col-byte
    lds_char* Lb = (lds_char*)&sbuf[0];

    const char* ap[4]; int aOff[4];
    #pragma unroll
    for (int s = 0; s < 4; ++s) {
        ap[s] = (const char*)xb + ((size_t)(m0 + w*32 + s*8 + lrow) << 10) + scb;
        aOff[s] = (w*4 + s) * 1024;
    }
    const char* wp[6]; int wOff[6];
    #pragma unroll
    for (int s = 0; s < 6; ++s) {
        int jj = w*6 + s;                 // 0..23 over [3][64] rows /8
        int g  = jj >> 3;
        int hg = (jj & 7) * 8 + lrow;
        wp[s] = (const char*)wb + ((size_t)(g*Hh + n0 + hg) << 10) + scb;
        wOff[s] = 16384 + jj * 1024;
    }

    // ---- fragment read offsets (swizzled) ----
    const int arow  = wm*64 + (lane & 15);
    const int wrow  = wn*32 + (lane & 15);
    const int sw    = (lane & 7) << 4;
    int acol[2];
    #pragma unroll
    for (int s = 0; s < 2; ++s)
        acol[s] = ((s*64) | ((lane >> 4) * 16)) ^ sw;

    f32x4 acc[3][4][2];
    #pragma unroll
    for (int g = 0; g < 3; ++g)
        #pragma unroll
        for (int mi = 0; mi < 4; ++mi)
            #pragma unroll
            for (int ni = 0; ni < 2; ++ni)
                acc[g][mi][ni] = (f32x4){0.f,0.f,0.f,0.f};

    auto STAGE = [&](int bo) {           // issue 10 global_load_lds, advance ptrs
        #pragma unroll
        for (int s = 0; s < 4; ++s) { gl2lds16(ap[s], Lb + bo + aOff[s]); ap[s] += 2*BK; }
        #pragma unroll
        for (int s = 0; s < 6; ++s) { gl2lds16(wp[s], Lb + bo + wOff[s]); wp[s] += 2*BK; }
    };
    auto COMPUTE = [&](int bo) {
        const char* sA = (const char*)&sbuf[0] + bo;
        #pragma unroll
        for (int s = 0; s < 2; ++s) {
            bf16x8 a[4];
            #pragma unroll
            for (int mi = 0; mi < 4; ++mi)
                a[mi] = *(const bf16x8*)(sA + ((arow + mi*16) << 7) + acol[s]);
            #pragma unroll
            for (int g = 0; g < 3; ++g) {
                bf16x8 w0 = *(const bf16x8*)(sA + 16384 + g*8192 + (wrow << 7) + acol[s]);
                bf16x8 w1 = *(const bf16x8*)(sA + 16384 + g*8192 + ((wrow + 16) << 7) + acol[s]);
                #pragma unroll
                for (int mi = 0; mi < 4; ++mi) {
                    acc[g][mi][0] = __builtin_amdgcn_mfma_f32_16x16x32_bf16(a[mi], w0, acc[g][mi][0], 0,0,0);
                    acc[g][mi][1] = __builtin_amdgcn_mfma_f32_16x16x32_bf16(a[mi], w1, acc[g][mi][1], 0,0,0);
                }
            }
        }
    };

    // prologue: tile 0 -> buf0
    STAGE(0);
    __syncthreads();                       // drains vmcnt(0): tile 0 visible

    // steady state: 8 K-tiles total, manually 2-unrolled for static buffer select
    #pragma unroll 1
    for (int i = 0; i < 3; ++i) {
        STAGE(LDSHALFB); COMPUTE(0); __syncthreads();
        STAGE(0);        COMPUTE(LDSHALFB); __syncthreads();
    }
    STAGE(LDSHALFB); COMPUTE(0); __syncthreads();
    COMPUTE(LDSHALFB);

    // ---- epilogue: fg = I/(F+I), ig = F/(F+I), F=1+e^-zf, I=1+e^-zi ----
    const int col = lane & 15;
    const int rb  = (lane >> 4) * 4;
    #pragma unroll
    for (int ni = 0; ni < 2; ++ni) {
        const int h = n0 + wn*32 + ni*16 + col;
        const float bfv = b_f[h], biv = b_i[h], bhv = b_h[h];
        #pragma unroll
        for (int mi = 0; mi < 4; ++mi) {
            #pragma unroll
            for (int r = 0; r < 4; ++r) {
                const int m = m0 + wm*64 + mi*16 + rb + r;
                float zf = acc[0][mi][ni][r] + bfv;
                float zi = acc[1][mi][ni][r] + biv;
                float zh = acc[2][mi][ni][r] + bhv;
                float ef = __expf(fminf(-zf, 60.0f));
                float ei = __expf(fminf(-zi, 60.0f));
                float rr = __builtin_amdgcn_rcpf(2.0f + ef + ei);
                float fg = (1.0f + ei) * rr;
                float ig = (1.0f + ef) * rr;
                float eh = __expf(fminf(-zh, 60.0f));
                float gv = (zh >= 0.0f) ? (zh + 0.5f) : __builtin_amdgcn_rcpf(1.0f + eh);
                float vv = ig * gv;
                FV[(size_t)m * Hh + h] = (u32)f2bf(fg) | ((u32)f2bf(vv) << 16);
            }
        }
    }
}

// ---------------- scan pass 1: per-chunk composites ----------------
__global__ void scan_pass1(const u32* __restrict__ FV,
                           float2* __restrict__ Fc2, float2* __restrict__ Vc2)
{
    const int t2 = threadIdx.x;               // h-pair 0..255
    const int b = blockIdx.x, ch = blockIdx.y;
    const uint2* p = (const uint2*)FV;
    size_t base = ((size_t)b * Tt + (size_t)ch * CLEN) * (Hh/2) + t2;
    float F0=1.f, V0=0.f, F1=1.f, V1=0.f;
    #pragma unroll 8
    for (int t = 0; t < CLEN; ++t) {
        uint2 fv = p[base + (size_t)t * (Hh/2)];
        V0 = fmaf(bf2f_lo(fv.x), V0, bf2f_hi(fv.x)); F0 *= bf2f_lo(fv.x);
        V1 = fmaf(bf2f_lo(fv.y), V1, bf2f_hi(fv.y)); F1 *= bf2f_lo(fv.y);
    }
    int ci = (b * NCHUNK + ch) * (Hh/2) + t2;
    Fc2[ci] = make_float2(F0, F1);
    Vc2[ci] = make_float2(V0, V1);
}

// ---------------- scan pass 2: scan over chunk composites ----------------
__global__ void scan_pass2(const float* __restrict__ h0,
                           const float* __restrict__ Fc, const float* __restrict__ Vc,
                           float* __restrict__ Hs)
{
    int h = threadIdx.x;      // 512
    int b = blockIdx.x;       // 8
    float x = h0[b * Hh + h];
    float hh = (x >= 0.f) ? (x + 0.5f) : __builtin_amdgcn_rcpf(1.f + __expf(-x));
    #pragma unroll 8
    for (int ch = 0; ch < NCHUNK; ++ch) {
        int ci = (b * NCHUNK + ch) * Hh + h;
        Hs[ci] = hh;
        hh = fmaf(Fc[ci], hh, Vc[ci]);
    }
}

// ---------------- scan pass 3: apply chunks, write outputs ----------------
__global__ void scan_pass3(const u32* __restrict__ FV,
                           const float2* __restrict__ Hs2, float2* __restrict__ out2)
{
    const int t2 = threadIdx.x;
    const int b = blockIdx.x, ch = blockIdx.y;
    const uint2* p = (const uint2*)FV;
    float2 hh = Hs2[(b * NCHUNK + ch) * (Hh/2) + t2];
    size_t base = ((size_t)b * Tt + (size_t)ch * CLEN) * (Hh/2) + t2;
    #pragma unroll 4
    for (int t = 0; t < CLEN; ++t) {
        size_t idx = base + (size_t)t * (Hh/2);
        uint2 fv = p[idx];
        hh.x = fmaf(bf2f_lo(fv.x), hh.x, bf2f_hi(fv.x));
        hh.y = fmaf(bf2f_lo(fv.y), hh.y, bf2f_hi(fv.y));
        out2[idx] = hh;
    }
}

extern "C" void kernel_launch(void* const* d_in, const int* in_sizes, int n_in,
                              void* d_out, int out_size, void* d_ws, size_t ws_size,
                              hipStream_t stream) {
    const float* x   = (const float*)d_in[0];
    const float* h0  = (const float*)d_in[1];
    const float* W_f = (const float*)d_in[2];
    const float* b_f = (const float*)d_in[3];
    const float* W_i = (const float*)d_in[4];
    const float* b_i = (const float*)d_in[5];
    const float* W_h = (const float*)d_in[6];
    const float* b_h = (const float*)d_in[7];
    float* out = (float*)d_out;

    // workspace layout
    char* ws = (char*)d_ws;
    u16*  xb   = (u16*)ws;                                       // 32 MB
    u16*  wbuf = (u16*)(ws + (size_t)Mm * Dd * 2);               // 1.5 MB
    u32*  FV   = (u32*)(ws + (size_t)Mm * Dd * 2 + (size_t)3 * Hh * Dd * 2); // 64 MB
    float* Fc  = (float*)(FV + (size_t)Mm * Hh);                 // 1 MB
    float* Vc  = Fc + (size_t)Bb * NCHUNK * Hh;                  // 1 MB
    float* Hs  = Vc + (size_t)Bb * NCHUNK * Hh;                  // 1 MB

    // 0) converts
    {
        int n8 = Mm * Dd / 8;
        cvt_kernel<<<n8 / 256, 256, 0, stream>>>(x, xb, n8);
        int w8 = Hh * Dd / 8;
        dim3 gw(w8 / 256, 3);
        cvt_w_kernel<<<gw, 256, 0, stream>>>(W_f, W_i, W_h, wbuf, w8);
    }

    // 1) fused 3-gate GEMM + gate math
    gate_gemm<<<(Mm / BM) * (Hh / BN), 256, 0, stream>>>(xb, wbuf, b_f, b_i, b_h, FV);

    // 2) chunked scan
    {
        dim3 g1(Bb, NCHUNK);
        scan_pass1<<<g1, 256, 0, stream>>>(FV, (float2*)Fc, (float2*)Vc);
        scan_pass2<<<Bb, Hh, 0, stream>>>(h0, Fc, Vc, Hs);
        scan_pass3<<<g1, 256, 0, stream>>>(FV, (const float2*)Hs, (float2*)out);
    }
}

// Round 4
// 113.701 us; speedup vs baseline: 2.0993x; 1.0183x over previous
//
#include <hip/hip_runtime.h>
#include <hip/hip_bf16.h>
#include <cmath>

#define Bb 8
#define Tt 4096
#define Dd 512
#define Hh 512
#define Mm (Bb*Tt)

// GEMM tiling
#define BM 128
#define BN 64
#define BK 64
#define LDSHALF 20480           // u16 elems per buffer: (BM + 3*BN)*BK
#define LDSHALFB 40960          // bytes per buffer

// scan chunking
#define NCHUNK 64
#define CLEN (Tt/NCHUNK)   // 64

typedef unsigned short u16;
typedef unsigned int   u32;
typedef __attribute__((ext_vector_type(8))) short bf16x8;
typedef __attribute__((ext_vector_type(4))) float f32x4;
typedef __attribute__((address_space(3))) char lds_char;

__device__ __forceinline__ u16 f2bf(float f) {
    u32 u = __float_as_uint(f);
    u += 0x7fffu + ((u >> 16) & 1u);   // RNE
    return (u16)(u >> 16);
}
__device__ __forceinline__ float bf2f_lo(u32 p) { return __uint_as_float(p << 16); }
__device__ __forceinline__ float bf2f_hi(u32 p) { return __uint_as_float(p & 0xffff0000u); }

__device__ __forceinline__ void gl2lds16(const void* g, lds_char* l) {
    __builtin_amdgcn_global_load_lds(
        (const __attribute__((address_space(1))) u32*)g,
        (__attribute__((address_space(3))) u32*)l, 16, 0, 0);
}

// raw barrier with compiler-level memory fences on both sides (no vmcnt drain)
__device__ __forceinline__ void wave_barrier() {
    asm volatile("" ::: "memory");
    __builtin_amdgcn_s_barrier();
    asm volatile("" ::: "memory");
}
#define VMWAIT(n) asm volatile("s_waitcnt vmcnt(" #n ")" ::: "memory")

// ---------------- kernel 0a: fp32 -> bf16 convert (x) ----------------
__global__ void cvt_kernel(const float* __restrict__ in, u16* __restrict__ out, int n8) {
    int i = blockIdx.x * blockDim.x + threadIdx.x;
    if (i >= n8) return;
    float4 a = reinterpret_cast<const float4*>(in)[i*2];
    float4 b = reinterpret_cast<const float4*>(in)[i*2+1];
    union { u16 u[8]; uint4 v; } r;
    r.u[0]=f2bf(a.x); r.u[1]=f2bf(a.y); r.u[2]=f2bf(a.z); r.u[3]=f2bf(a.w);
    r.u[4]=f2bf(b.x); r.u[5]=f2bf(b.y); r.u[6]=f2bf(b.z); r.u[7]=f2bf(b.w);
    reinterpret_cast<uint4*>(out)[i] = r.v;
}

// ---------------- kernel 0b: convert the 3 weight matrices in one launch ----------------
__global__ void cvt_w_kernel(const float* __restrict__ wf, const float* __restrict__ wi,
                             const float* __restrict__ wh, u16* __restrict__ out, int n8) {
    int i = blockIdx.x * blockDim.x + threadIdx.x;
    if (i >= n8) return;
    const float* in = (blockIdx.y == 0) ? wf : (blockIdx.y == 1) ? wi : wh;
    u16* o = out + (size_t)blockIdx.y * Hh * Dd;
    float4 a = reinterpret_cast<const float4*>(in)[i*2];
    float4 b = reinterpret_cast<const float4*>(in)[i*2+1];
    union { u16 u[8]; uint4 v; } r;
    r.u[0]=f2bf(a.x); r.u[1]=f2bf(a.y); r.u[2]=f2bf(a.z); r.u[3]=f2bf(a.w);
    r.u[4]=f2bf(b.x); r.u[5]=f2bf(b.y); r.u[6]=f2bf(b.z); r.u[7]=f2bf(b.w);
    reinterpret_cast<uint4*>(o)[i] = r.v;
}

// ---------------- kernel 1: fused 3-gate GEMM + gate math + chunk composites ----------------
// LDS per buffer: A tile [128][64] bf16 (16 KB) then W tile [3*64][64] (24 KB),
// linear 128 B rows, XOR swizzle byte ^= ((row&7)<<4) on GLOBAL source and ds_read addr.
// Counted-vmcnt 2-buffer pipeline (T4): each STAGE = 10 global_load_lds per wave;
// s_waitcnt vmcnt(10) + s_barrier => previous tile landed, current prefetch in flight.
// Second barrier per tile protects WAR before restaging the just-read buffer.
// Epilogue additionally computes the per-chunk scan composites (wave wm owns one
// 64-row chunk): local 4-run compose + ordered butterfly across lane bits 4/5.
__global__ __launch_bounds__(256, 2)
void gate_gemm(const u16* __restrict__ xb,      // [Mm][Dd] bf16
               const u16* __restrict__ wb,      // [3][Hh][Dd] bf16
               const float* __restrict__ b_f, const float* __restrict__ b_i,
               const float* __restrict__ b_h,
               u32* __restrict__ FV,            // packed bf16 f | v<<16
               float* __restrict__ Fc, float* __restrict__ Vc)
{
    __shared__ __align__(128) u16 sbuf[2 * LDSHALF];   // 80 KB

    const int tid  = threadIdx.x;
    const int lane = tid & 63;
    const int w    = tid >> 6;
    const int wm   = w >> 1;    // 0..1
    const int wn   = w & 1;     // 0..1

    // XCD-bijective swizzle: consecutive-n blocks stay on one XCD -> A panel L2-hot
    const int bid = blockIdx.x;
    const int lg  = (bid >> 3) + (bid & 7) * ((int)gridDim.x >> 3);
    const int m0  = (lg >> 3) * BM;
    const int n0  = (lg & 7) * BN;

    // ---- staging addresses (pre-swizzled global source, linear LDS dest) ----
    const int lrow = lane >> 3;                       // row within 8-row group
    const int scb  = ((lane & 7) * 16) ^ (lrow << 4); // swizzled col-byte
    lds_char* Lb = (lds_char*)&sbuf[0];

    const char* ap[4]; int aOff[4];
    #pragma unroll
    for (int s = 0; s < 4; ++s) {
        ap[s] = (const char*)xb + ((size_t)(m0 + w*32 + s*8 + lrow) << 10) + scb;
        aOff[s] = (w*4 + s) * 1024;
    }
    const char* wp[6]; int wOff[6];
    #pragma unroll
    for (int s = 0; s < 6; ++s) {
        int jj = w*6 + s;                 // 0..23 over [3][64] rows /8
        int g  = jj >> 3;
        int hg = (jj & 7) * 8 + lrow;
        wp[s] = (const char*)wb + ((size_t)(g*Hh + n0 + hg) << 10) + scb;
        wOff[s] = 16384 + jj * 1024;
    }

    // ---- fragment read offsets (swizzled) ----
    const int arow  = wm*64 + (lane & 15);
    const int wrow  = wn*32 + (lane & 15);
    const int sw    = (lane & 7) << 4;
    int acol[2];
    #pragma unroll
    for (int s = 0; s < 2; ++s)
        acol[s] = ((s*64) | ((lane >> 4) * 16)) ^ sw;

    f32x4 acc[3][4][2];
    #pragma unroll
    for (int g = 0; g < 3; ++g)
        #pragma unroll
        for (int mi = 0; mi < 4; ++mi)
            #pragma unroll
            for (int ni = 0; ni < 2; ++ni)
                acc[g][mi][ni] = (f32x4){0.f,0.f,0.f,0.f};

    auto STAGE = [&](int bo) {           // issue 10 global_load_lds, advance ptrs
        #pragma unroll
        for (int s = 0; s < 4; ++s) { gl2lds16(ap[s], Lb + bo + aOff[s]); ap[s] += 2*BK; }
        #pragma unroll
        for (int s = 0; s < 6; ++s) { gl2lds16(wp[s], Lb + bo + wOff[s]); wp[s] += 2*BK; }
    };
    auto COMPUTE = [&](int bo) {
        const char* sA = (const char*)&sbuf[0] + bo;
        #pragma unroll
        for (int s = 0; s < 2; ++s) {
            bf16x8 a[4], wv[3][2];
            #pragma unroll
            for (int mi = 0; mi < 4; ++mi)
                a[mi] = *(const bf16x8*)(sA + ((arow + mi*16) << 7) + acol[s]);
            #pragma unroll
            for (int g = 0; g < 3; ++g) {
                wv[g][0] = *(const bf16x8*)(sA + 16384 + g*8192 + (wrow << 7) + acol[s]);
                wv[g][1] = *(const bf16x8*)(sA + 16384 + g*8192 + ((wrow + 16) << 7) + acol[s]);
            }
            __builtin_amdgcn_s_setprio(1);
            #pragma unroll
            for (int g = 0; g < 3; ++g)
                #pragma unroll
                for (int mi = 0; mi < 4; ++mi) {
                    acc[g][mi][0] = __builtin_amdgcn_mfma_f32_16x16x32_bf16(a[mi], wv[g][0], acc[g][mi][0], 0,0,0);
                    acc[g][mi][1] = __builtin_amdgcn_mfma_f32_16x16x32_bf16(a[mi], wv[g][1], acc[g][mi][1], 0,0,0);
                }
            __builtin_amdgcn_s_setprio(0);
        }
    };

    // prologue: tile 0 -> buf0 (10 loads in flight)
    STAGE(0);

    // steady state: 8 K-tiles, counted vmcnt — prefetch never drained
    #pragma unroll 1
    for (int i = 0; i < 3; ++i) {
        STAGE(LDSHALFB); VMWAIT(10); wave_barrier(); __builtin_amdgcn_sched_barrier(0);
        COMPUTE(0);       wave_barrier();
        STAGE(0);        VMWAIT(10); wave_barrier(); __builtin_amdgcn_sched_barrier(0);
        COMPUTE(LDSHALFB); wave_barrier();
    }
    STAGE(LDSHALFB); VMWAIT(10); wave_barrier(); __builtin_amdgcn_sched_barrier(0);
    COMPUTE(0);       wave_barrier();
    VMWAIT(0);        wave_barrier(); __builtin_amdgcn_sched_barrier(0);
    COMPUTE(LDSHALFB);

    // ---- epilogue: gates + FV store + fused chunk composites ----
    // fg = I/(F+I), ig = F/(F+I), F=1+e^-zf, I=1+e^-zi
    const int col = lane & 15;
    const int lg4 = lane >> 4;
    const int rb  = lg4 * 4;
    const int gch = (m0 + wm*64) >> 6;     // global chunk index == (b*NCHUNK+ch)

    #pragma unroll
    for (int ni = 0; ni < 2; ++ni) {
        const int h = n0 + wn*32 + ni*16 + col;
        const float bfv = b_f[h], biv = b_i[h], bhv = b_h[h];
        float Fr = 1.0f, Vr = 0.0f;        // running chunk composite
        #pragma unroll
        for (int mi = 0; mi < 4; ++mi) {
            float F4 = 1.0f, V4 = 0.0f;    // local 4-row run composite
            #pragma unroll
            for (int r = 0; r < 4; ++r) {
                const int m = m0 + wm*64 + mi*16 + rb + r;
                float zf = acc[0][mi][ni][r] + bfv;
                float zi = acc[1][mi][ni][r] + biv;
                float zh = acc[2][mi][ni][r] + bhv;
                float ef = __expf(fminf(-zf, 60.0f));
                float ei = __expf(fminf(-zi, 60.0f));
                float rr = __builtin_amdgcn_rcpf(2.0f + ef + ei);
                float fg = (1.0f + ei) * rr;
                float ig = (1.0f + ef) * rr;
                float eh = __expf(fminf(-zh, 60.0f));
                float gv = (zh >= 0.0f) ? (zh + 0.5f) : __builtin_amdgcn_rcpf(1.0f + eh);
                float vv = ig * gv;
                u32 pk = (u32)f2bf(fg) | ((u32)f2bf(vv) << 16);
                FV[(size_t)m * Hh + h] = pk;
                // use the rounded values so composites match pass3's replay
                float f_ = bf2f_lo(pk), v_ = bf2f_hi(pk);
                V4 = fmaf(f_, V4, v_);
                F4 *= f_;
            }
            // ordered butterfly compose across lane bits 4 and 5
            {
                float Fp = __shfl_xor(F4, 16), Vp = __shfl_xor(V4, 16);
                float Fl = (lane & 16) ? Fp : F4, Vl = (lane & 16) ? Vp : V4;
                float Fh = (lane & 16) ? F4 : Fp, Vh = (lane & 16) ? V4 : Vp;
                F4 = Fh * Fl; V4 = fmaf(Fh, Vl, Vh);
                Fp = __shfl_xor(F4, 32); Vp = __shfl_xor(V4, 32);
                Fl = (lane & 32) ? Fp : F4; Vl = (lane & 32) ? Vp : V4;
                Fh = (lane & 32) ? F4 : Fp; Vh = (lane & 32) ? V4 : Vp;
                F4 = Fh * Fl; V4 = fmaf(Fh, Vl, Vh);
            }
            Vr = fmaf(F4, Vr, V4);
            Fr = F4 * Fr;
        }
        if (lg4 == 0) {
            Fc[(size_t)gch * Hh + h] = Fr;
            Vc[(size_t)gch * Hh + h] = Vr;
        }
    }
}

// ---------------- scan pass 2: scan over chunk composites ----------------
__global__ void scan_pass2(const float* __restrict__ h0,
                           const float* __restrict__ Fc, const float* __restrict__ Vc,
                           float* __restrict__ Hs)
{
    int h = threadIdx.x;      // 512
    int b = blockIdx.x;       // 8
    float x = h0[b * Hh + h];
    float hh = (x >= 0.f) ? (x + 0.5f) : __builtin_amdgcn_rcpf(1.f + __expf(-x));
    #pragma unroll 8
    for (int ch = 0; ch < NCHUNK; ++ch) {
        int ci = (b * NCHUNK + ch) * Hh + h;
        Hs[ci] = hh;
        hh = fmaf(Fc[ci], hh, Vc[ci]);
    }
}

// ---------------- scan pass 3: apply chunks, write outputs ----------------
__global__ void scan_pass3(const u32* __restrict__ FV,
                           const float2* __restrict__ Hs2, float2* __restrict__ out2)
{
    const int t2 = threadIdx.x;
    const int b = blockIdx.x, ch = blockIdx.y;
    const uint2* p = (const uint2*)FV;
    float2 hh = Hs2[(b * NCHUNK + ch) * (Hh/2) + t2];
    size_t base = ((size_t)b * Tt + (size_t)ch * CLEN) * (Hh/2) + t2;
    #pragma unroll 4
    for (int t = 0; t < CLEN; ++t) {
        size_t idx = base + (size_t)t * (Hh/2);
        uint2 fv = p[idx];
        hh.x = fmaf(bf2f_lo(fv.x), hh.x, bf2f_hi(fv.x));
        hh.y = fmaf(bf2f_lo(fv.y), hh.y, bf2f_hi(fv.y));
        out2[idx] = hh;
    }
}

extern "C" void kernel_launch(void* const* d_in, const int* in_sizes, int n_in,
                              void* d_out, int out_size, void* d_ws, size_t ws_size,
                              hipStream_t stream) {
    const float* x   = (const float*)d_in[0];
    const float* h0  = (const float*)d_in[1];
    const float* W_f = (const float*)d_in[2];
    const float* b_f = (const float*)d_in[3];
    const float* W_i = (const float*)d_in[4];
    const float* b_i = (const float*)d_in[5];
    const float* W_h = (const float*)d_in[6];
    const float* b_h = (const float*)d_in[7];
    float* out = (float*)d_out;

    // workspace layout
    char* ws = (char*)d_ws;
    u16*  xb   = (u16*)ws;                                       // 32 MB
    u16*  wbuf = (u16*)(ws + (size_t)Mm * Dd * 2);               // 1.5 MB
    u32*  FV   = (u32*)(ws + (size_t)Mm * Dd * 2 + (size_t)3 * Hh * Dd * 2); // 64 MB
    float* Fc  = (float*)(FV + (size_t)Mm * Hh);                 // 1 MB
    float* Vc  = Fc + (size_t)Bb * NCHUNK * Hh;                  // 1 MB
    float* Hs  = Vc + (size_t)Bb * NCHUNK * Hh;                  // 1 MB

    // 0) converts
    {
        int n8 = Mm * Dd / 8;
        cvt_kernel<<<n8 / 256, 256, 0, stream>>>(x, xb, n8);
        int w8 = Hh * Dd / 8;
        dim3 gw(w8 / 256, 3);
        cvt_w_kernel<<<gw, 256, 0, stream>>>(W_f, W_i, W_h, wbuf, w8);
    }

    // 1) fused 3-gate GEMM + gate math + chunk composites
    gate_gemm<<<(Mm / BM) * (Hh / BN), 256, 0, stream>>>(xb, wbuf, b_f, b_i, b_h, FV, Fc, Vc);

    // 2) chunked scan (pass1 now fused into gate_gemm epilogue)
    scan_pass2<<<Bb, Hh, 0, stream>>>(h0, Fc, Vc, Hs);
    {
        dim3 g1(Bb, NCHUNK);
        scan_pass3<<<g1, 256, 0, stream>>>(FV, (const float2*)Hs, (float2*)out);
    }
}